// Round 3
// baseline (159.822 us; speedup 1.0000x reference)
//
#include <hip/hip_runtime.h>
#include <hip/hip_bf16.h>

typedef __hip_bfloat16 bf16;
typedef unsigned short u16;
typedef __attribute__((ext_vector_type(8))) short bf16x8;
typedef __attribute__((ext_vector_type(16))) float f32x16;

static constexpr int Bn = 8;
static constexpr int C = 512;
static constexpr int S = 1024;
static constexpr int NH = 8;
static constexpr int HD = 64;
static constexpr int CPG = 16;
#define EPSV 1e-5f
#define QSCALE 0.18033688011112042f  /* 0.125 * log2(e): folds attn scale + exp->exp2 */

__device__ __forceinline__ u16 f2bf(float f) {
    bf16 h = __float2bfloat16(f);
    return *reinterpret_cast<u16*>(&h);
}
__device__ __forceinline__ unsigned pack_bf2(float a, float b) {
    __hip_bfloat162 h = __float22bfloat162_rn(make_float2(a, b));
    return *reinterpret_cast<unsigned*>(&h);
}

// v_permlane32_swap_b32: x = {a.lo | b.lo-from-counterpart}, y = {a.hi-from-counterpart | b.hi}
__device__ __forceinline__ void plswap32(unsigned a, unsigned b, unsigned& x, unsigned& y) {
    typedef __attribute__((ext_vector_type(2))) int v2i;
    v2i r = __builtin_amdgcn_permlane32_swap((int)a, (int)b, false, false);
    x = (unsigned)r[0];
    y = (unsigned)r[1];
}

// async global->LDS, 16B per lane; LDS dest = wave-uniform base + lane*16
__device__ __forceinline__ void async_copy16(const void* g, void* l) {
    __builtin_amdgcn_global_load_lds(
        (const __attribute__((address_space(1))) void*)g,
        (__attribute__((address_space(3))) void*)l, 16, 0, 0);
}

// ---- prep: blocks 0-255 fused GroupNorm (stats + apply + transpose, group
//      staged in 64 KB LDS — x read ONCE); blocks 256-1279 weight fp32->bf16 ----
__global__ __launch_bounds__(256) void prep(const float* __restrict__ x,
                                            const float* __restrict__ wqkv,
                                            const float* __restrict__ wproj,
                                            const float* __restrict__ gamma,
                                            const float* __restrict__ beta,
                                            u16* __restrict__ wbf,
                                            u16* __restrict__ xnt) {
    const int tid = threadIdx.x;
    __shared__ float xs[CPG * S];  // 64 KB: [c][s] for this (b,g) group
    if (blockIdx.x < 256) {
        const int bg = blockIdx.x;         // b*32 + g
        const int b = bg >> 5, g = bg & 31;
        const size_t base = (size_t)bg * CPG * S;  // group contiguous in x[b][c][s]
        const int N = CPG * S;  // 16384
        float sum = 0.f, sq = 0.f;
        for (int i = tid * 4; i < N; i += 1024) {
            float4 v = *reinterpret_cast<const float4*>(&x[base + i]);
            sum += v.x + v.y + v.z + v.w;
            sq += v.x * v.x + v.y * v.y + v.z * v.z + v.w * v.w;
            *reinterpret_cast<float4*>(&xs[i]) = v;  // stride-1 b128: conflict-free
        }
#pragma unroll
        for (int off = 32; off > 0; off >>= 1) {
            sum += __shfl_down(sum, off, 64);
            sq  += __shfl_down(sq,  off, 64);
        }
        __shared__ float s0[4], s1[4];
        __shared__ float sgb[32];  // gamma*rstd-ready params: [0..15]=gamma,[16..31]=beta
        __shared__ float smu, srstd;
        if ((tid & 63) == 0) { s0[tid >> 6] = sum; s1[tid >> 6] = sq; }
        if (tid < 16) {
            sgb[tid] = gamma[g * CPG + tid];
            sgb[16 + tid] = beta[g * CPG + tid];
        }
        __syncthreads();
        if (tid == 0) {
            float a  = s0[0] + s0[1] + s0[2] + s0[3];
            float b2 = s1[0] + s1[1] + s1[2] + s1[3];
            float mu = a / (float)N;
            float var = fmaxf(b2 / (float)N - mu * mu, 0.f);
            smu = mu;
            srstd = rsqrtf(var + EPSV);
        }
        __syncthreads();
        const float mu = smu, rstd = srstd;
        // apply + transpose: xnt[b][s][g*16 + c], 16 B store per (s, half-group)
#pragma unroll
        for (int it = 0; it < 8; ++it) {
            int idx = it * 256 + tid;       // 2048 = 1024 s x 2 half-groups
            int s = idx >> 1, jh = idx & 1;
            u16 t8[8];
#pragma unroll
            for (int j = 0; j < 8; ++j) {
                int c = jh * 8 + j;
                float v = (xs[c * S + s] - mu) * rstd;  // bank=s%32, lane-pairs 2-way: free
                t8[j] = f2bf(v * sgb[c] + sgb[16 + c]);
            }
            *reinterpret_cast<uint4*>(&xnt[(size_t)(b * S + s) * C + g * CPG + jh * 8]) =
                *reinterpret_cast<uint4*>(t8);
        }
    } else {
        int idx = (blockIdx.x - 256) * 1024 + tid * 4;  // 2048*512 total
        float4 v;
        float sc = 1.f;
        if (idx < 1536 * 512) {
            v = *reinterpret_cast<const float4*>(&wqkv[idx]);
            if (idx < 512 * 512) sc = QSCALE;  // Q rows
        } else {
            v = *reinterpret_cast<const float4*>(&wproj[idx - 1536 * 512]);
        }
        u16 t[4] = {f2bf(v.x * sc), f2bf(v.y * sc), f2bf(v.z * sc), f2bf(v.w * sc)};
        *reinterpret_cast<uint2*>(&wbf[idx]) = *reinterpret_cast<uint2*>(t);
    }
}

// ---- qkv GEMM: 128x128 tile, BK=64, 2 barriers/iter, 32x32x16 MFMA ----
// o<1024 (q,k) -> qkvT[b][s][1024] transposed; o>=1024 (v) -> qkvV[b][512][S].
// 32x32 C/D: col=lane&31, row=(reg&3)+8*(reg>>2)+4*(lane>>5)  [m74/m101]
__global__ __launch_bounds__(256) void qkv_gemm(const u16* __restrict__ Wb,
                                                const u16* __restrict__ Xt,
                                                const float* __restrict__ bias,
                                                u16* __restrict__ qkvT,
                                                u16* __restrict__ qkvV) {
    const int K = 512;
    const int b = blockIdx.z, o0 = blockIdx.y * 128, s0 = blockIdx.x * 128;
    const int tid = threadIdx.x;
    const int lane = tid & 63, w = tid >> 6;
    const int l31 = lane & 31, half = lane >> 5;
    const int wr = w >> 1, wc = w & 1;
    __shared__ u16 As[128 * 64];  // [o][k-chunk]: chunk c at slot c^(row&7)
    __shared__ u16 Bs[128 * 64];
    f32x16 acc[2][2] = {};
    const u16* Xb = Xt + (size_t)(b * S + s0) * K;
    for (int k0 = 0; k0 < K; k0 += 64) {
#pragma unroll
        for (int i = 0; i < 4; ++i) {
            int ci = w * 4 + i;
            int r = ci * 8 + (lane >> 3);
            int c = (lane & 7) ^ (r & 7);
            async_copy16(&Wb[(size_t)(o0 + r) * K + k0 + c * 8], &As[ci * 512]);
            async_copy16(&Xb[(size_t)r * K + k0 + c * 8], &Bs[ci * 512]);
        }
        __syncthreads();
#pragma unroll
        for (int kk = 0; kk < 4; ++kk) {
            int c8 = kk * 2 + half;
            bf16x8 af[2], bfr[2];
#pragma unroll
            for (int mt = 0; mt < 2; ++mt) {
                int R = wr * 64 + mt * 32 + l31;
                af[mt] = *reinterpret_cast<const bf16x8*>(
                    &As[R * 64 + ((c8 ^ (R & 7)) << 3)]);
            }
#pragma unroll
            for (int nt = 0; nt < 2; ++nt) {
                int R = wc * 64 + nt * 32 + l31;
                bfr[nt] = *reinterpret_cast<const bf16x8*>(
                    &Bs[R * 64 + ((c8 ^ (R & 7)) << 3)]);
            }
#pragma unroll
            for (int mt = 0; mt < 2; ++mt)
#pragma unroll
                for (int nt = 0; nt < 2; ++nt)
                    acc[mt][nt] = __builtin_amdgcn_mfma_f32_32x32x16_bf16(
                        af[mt], bfr[nt], acc[mt][nt], 0, 0, 0);
        }
        __syncthreads();
    }
    if (o0 < 1024) {
        // q,k -> [b][s][1024]; q bias gets QSCALE (matches pre-scaled Q weights)
        float bsc = (o0 < 512) ? QSCALE : 1.f;
#pragma unroll
        for (int mt = 0; mt < 2; ++mt) {
#pragma unroll
            for (int g = 0; g < 4; ++g) {
                int o_b = o0 + wr * 64 + mt * 32 + g * 8 + half * 4;
                float4 bz = *reinterpret_cast<const float4*>(&bias[o_b]);
#pragma unroll
                for (int nt = 0; nt < 2; ++nt) {
                    int s = s0 + wc * 64 + nt * 32 + l31;
                    uint2 pk;
                    pk.x = pack_bf2(acc[mt][nt][g * 4 + 0] + bz.x * bsc,
                                    acc[mt][nt][g * 4 + 1] + bz.y * bsc);
                    pk.y = pack_bf2(acc[mt][nt][g * 4 + 2] + bz.z * bsc,
                                    acc[mt][nt][g * 4 + 3] + bz.w * bsc);
                    *reinterpret_cast<uint2*>(&qkvT[(size_t)(b * S + s) * 1024 + o_b]) = pk;
                }
            }
        }
    } else {
        // v -> [b][v-channel][S]
#pragma unroll
        for (int mt = 0; mt < 2; ++mt) {
#pragma unroll
            for (int g = 0; g < 4; ++g) {
                int o_b = o0 - 1024 + wr * 64 + mt * 32 + g * 8 + half * 4;
                float4 bz = *reinterpret_cast<const float4*>(&bias[1024 + o_b]);
                float bza[4] = {bz.x, bz.y, bz.z, bz.w};
#pragma unroll
                for (int nt = 0; nt < 2; ++nt) {
                    int s = s0 + wc * 64 + nt * 32 + l31;
#pragma unroll
                    for (int r = 0; r < 4; ++r)
                        qkvV[(size_t)(b * 512 + o_b + r) * S + s] =
                            f2bf(acc[mt][nt][g * 4 + r] + bza[r]);
                }
            }
        }
    }
}

// ---- proj GEMM: 64(o)x128(s) tile -> 512 blocks = 2/CU (latency hiding) ----
// fp32 output = acc + bias + residual (fp32 x).
__global__ __launch_bounds__(256) void proj_gemm(const u16* __restrict__ Wb,
                                                 const u16* __restrict__ Xt,
                                                 const float* __restrict__ bias,
                                                 const float* __restrict__ resid,
                                                 float* __restrict__ Yf) {
    const int K = 512;
    const int b = blockIdx.z, o0 = blockIdx.y * 64, s0 = blockIdx.x * 128;
    const int tid = threadIdx.x;
    const int lane = tid & 63, w = tid >> 6;
    const int l31 = lane & 31, half = lane >> 5;
    const int wr = w >> 1, wc = w & 1;   // wave: 32 o x 64 s
    __shared__ u16 As[64 * 64];   // 8 KB
    __shared__ u16 Bs[128 * 64];  // 16 KB
    f32x16 acc[2] = {};           // nt over s
    const u16* Xb = Xt + (size_t)(b * S + s0) * K;
    for (int k0 = 0; k0 < K; k0 += 64) {
#pragma unroll
        for (int i = 0; i < 2; ++i) {
            int ci = w * 2 + i;
            int r = ci * 8 + (lane >> 3);
            int c = (lane & 7) ^ (r & 7);
            async_copy16(&Wb[(size_t)(o0 + r) * K + k0 + c * 8], &As[ci * 512]);
        }
#pragma unroll
        for (int i = 0; i < 4; ++i) {
            int ci = w * 4 + i;
            int r = ci * 8 + (lane >> 3);
            int c = (lane & 7) ^ (r & 7);
            async_copy16(&Xb[(size_t)r * K + k0 + c * 8], &Bs[ci * 512]);
        }
        __syncthreads();
#pragma unroll
        for (int kk = 0; kk < 4; ++kk) {
            int c8 = kk * 2 + half;
            int Ra = wr * 32 + l31;
            bf16x8 af = *reinterpret_cast<const bf16x8*>(
                &As[Ra * 64 + ((c8 ^ (Ra & 7)) << 3)]);
#pragma unroll
            for (int nt = 0; nt < 2; ++nt) {
                int R = wc * 64 + nt * 32 + l31;
                bf16x8 bfr = *reinterpret_cast<const bf16x8*>(
                    &Bs[R * 64 + ((c8 ^ (R & 7)) << 3)]);
                acc[nt] = __builtin_amdgcn_mfma_f32_32x32x16_bf16(
                    af, bfr, acc[nt], 0, 0, 0);
            }
        }
        __syncthreads();
    }
#pragma unroll
    for (int g = 0; g < 4; ++g) {
        int o_b = o0 + wr * 32 + g * 8 + half * 4;
        float4 bz = *reinterpret_cast<const float4*>(&bias[o_b]);
        float bza[4] = {bz.x, bz.y, bz.z, bz.w};
#pragma unroll
        for (int nt = 0; nt < 2; ++nt) {
            int s = s0 + wc * 64 + nt * 32 + l31;
#pragma unroll
            for (int r = 0; r < 4; ++r) {
                size_t idx = (size_t)(b * C + o_b + r) * S + s;
                Yf[idx] = acc[nt][g * 4 + r] + bza[r] + resid[idx];
            }
        }
    }
}

// ---- MFMA flash attention: 2-wave blocks, 64 queries/wave (2 query-tiles),
//      KVBLK=64 double-buffered. Each K/V fragment is read from LDS ONCE and
//      feeds TWO MFMAs (one per query-tile) -> 16 b128 : 32 MFMA per wave-iter
//      (halved LDS-read traffic per MFMA vs 1-qt/wave).
// Grid swizzle: blockIdx.x = b*8+h (stride-64 blocks share (b,h) -> same XCD).
// T12: swapped QK^T -> P lane-local; cvt_pk + permlane32_swap builds PV
// B-fragments in-register (no P LDS round-trip).
__global__ __launch_bounds__(128) void attn_mfma(const u16* __restrict__ qkvT,
                                                 const u16* __restrict__ qkvV,
                                                 u16* __restrict__ houtt) {
    const int b = blockIdx.x >> 3, h = blockIdx.x & 7, q0 = blockIdx.y * 128;
    const int tid = threadIdx.x;
    const int lane = tid & 63, w = tid >> 6;   // w in {0,1}
    const int l31 = lane & 31, half = lane >> 5;
    __shared__ u16 ks[2][64 * 64];  // [buf][key][d] chunk-swizzled (16 KB)
    __shared__ u16 vs[2][64 * 64];  // [buf][d][key] chunk-swizzled (16 KB)

    const u16* krow = qkvT + (size_t)b * S * 1024 + 512 + h * HD;
    const u16* vrow = qkvV + (size_t)(b * 512 + h * HD) * S;

    // Q fragments for 2 query-tiles: queries q0 + w*64 + qt*32 + l31
    bf16x8 qfrag[2][4];
#pragma unroll
    for (int qt = 0; qt < 2; ++qt) {
        const u16* qrow =
            qkvT + (size_t)(b * S + q0 + w * 64 + qt * 32 + l31) * 1024 + h * HD;
#pragma unroll
        for (int kk = 0; kk < 4; ++kk)
            qfrag[qt][kk] = *reinterpret_cast<const bf16x8*>(&qrow[kk * 16 + half * 8]);
    }

    const int r8 = lane >> 3;   // staging row within 8-row chunk-group
    const int cc = lane & 7;    // staging chunk col (pre-xor)

    // stage tile 0 (keys 0..63): 4 K-asyncs + 4 V-asyncs per thread (2 waves)
#pragma unroll
    for (int i = 0; i < 4; ++i) {
        int ci = w * 4 + i;
        int r = ci * 8 + r8;
        int c = cc ^ (r & 7);
        async_copy16(&krow[(size_t)r * 1024 + c * 8], &ks[0][ci * 512]);
        async_copy16(&vrow[(size_t)r * S + c * 8], &vs[0][ci * 512]);
    }
    __syncthreads();

    f32x16 o_acc[2][2] = {};   // [qt][nt]
    float l_i[2] = {0.f, 0.f};

    for (int t = 0; t < 16; ++t) {
        const int cur = t & 1, nxt = cur ^ 1;
        if (t < 15) {
            int kt = (t + 1) * 64;
#pragma unroll
            for (int i = 0; i < 4; ++i) {
                int ci = w * 4 + i;
                int r = ci * 8 + r8;
                int c = cc ^ (r & 7);
                async_copy16(&krow[(size_t)(kt + r) * 1024 + c * 8], &ks[nxt][ci * 512]);
                async_copy16(&vrow[(size_t)r * S + kt + c * 8], &vs[nxt][ci * 512]);
            }
        }
        // ---- S^T = K Q^T : each kf read once, used by both query-tiles ----
        f32x16 s_acc[2][2] = {};   // [qt][mt]
        __builtin_amdgcn_s_setprio(1);
#pragma unroll
        for (int mt = 0; mt < 2; ++mt) {
            int r = mt * 32 + l31;
            bf16x8 kf[4];
#pragma unroll
            for (int kk = 0; kk < 4; ++kk)
                kf[kk] = *reinterpret_cast<const bf16x8*>(
                    &ks[cur][r * 64 + (((kk * 2 + half) ^ (r & 7)) << 3)]);
#pragma unroll
            for (int qt = 0; qt < 2; ++qt)
#pragma unroll
                for (int kk = 0; kk < 4; ++kk)
                    s_acc[qt][mt] = __builtin_amdgcn_mfma_f32_32x32x16_bf16(
                        kf[kk], qfrag[qt][kk], s_acc[qt][mt], 0, 0, 0);
        }
        __builtin_amdgcn_s_setprio(0);
        // ---- max-free softmax: p = 2^s, in registers; per query-tile ----
        // lane (l31,half) holds P[q][key = mt*32 + g*8 + half*4 + r]
        bf16x8 pf[2][4];
#pragma unroll
        for (int qt = 0; qt < 2; ++qt) {
            float rsp0 = 0.f, rsp1 = 0.f, rsp2 = 0.f, rsp3 = 0.f;
#pragma unroll
            for (int mt = 0; mt < 2; ++mt)
#pragma unroll
                for (int g = 0; g < 4; ++g) {
                    float p0 = __builtin_amdgcn_exp2f(s_acc[qt][mt][g * 4 + 0]);
                    float p1 = __builtin_amdgcn_exp2f(s_acc[qt][mt][g * 4 + 1]);
                    float p2 = __builtin_amdgcn_exp2f(s_acc[qt][mt][g * 4 + 2]);
                    float p3 = __builtin_amdgcn_exp2f(s_acc[qt][mt][g * 4 + 3]);
                    s_acc[qt][mt][g * 4 + 0] = p0;
                    s_acc[qt][mt][g * 4 + 1] = p1;
                    s_acc[qt][mt][g * 4 + 2] = p2;
                    s_acc[qt][mt][g * 4 + 3] = p3;
                    rsp0 += p0; rsp1 += p1; rsp2 += p2; rsp3 += p3;
                }
            l_i[qt] += (rsp0 + rsp1) + (rsp2 + rsp3);
            // P^T B-frags in-register: pf[qt][kk][j] = P[q][kk*16 + half*8 + j]
#pragma unroll
            for (int mt = 0; mt < 2; ++mt)
#pragma unroll
                for (int gp = 0; gp < 2; ++gp) {
                    unsigned a_lo = pack_bf2(s_acc[qt][mt][gp * 8 + 0],
                                             s_acc[qt][mt][gp * 8 + 1]);
                    unsigned a_hi = pack_bf2(s_acc[qt][mt][gp * 8 + 2],
                                             s_acc[qt][mt][gp * 8 + 3]);
                    unsigned b_lo = pack_bf2(s_acc[qt][mt][gp * 8 + 4],
                                             s_acc[qt][mt][gp * 8 + 5]);
                    unsigned b_hi = pack_bf2(s_acc[qt][mt][gp * 8 + 6],
                                             s_acc[qt][mt][gp * 8 + 7]);
                    unsigned u0, u1, u2, u3;
                    plswap32(a_lo, b_lo, u0, u2);
                    plswap32(a_hi, b_hi, u1, u3);
                    union { unsigned u[4]; bf16x8 v; } wv;
                    wv.u[0] = u0; wv.u[1] = u1; wv.u[2] = u2; wv.u[3] = u3;
                    pf[qt][mt * 2 + gp] = wv.v;
                }
        }
        // ---- O^T += V^T P^T : each vf read once, used by both query-tiles ----
        __builtin_amdgcn_s_setprio(1);
#pragma unroll
        for (int nt = 0; nt < 2; ++nt) {
            int rv = nt * 32 + l31;
            bf16x8 vf[4];
#pragma unroll
            for (int kk = 0; kk < 4; ++kk)
                vf[kk] = *reinterpret_cast<const bf16x8*>(
                    &vs[cur][rv * 64 + (((kk * 2 + half) ^ (rv & 7)) << 3)]);
#pragma unroll
            for (int qt = 0; qt < 2; ++qt)
#pragma unroll
                for (int kk = 0; kk < 4; ++kk)
                    o_acc[qt][nt] = __builtin_amdgcn_mfma_f32_32x32x16_bf16(
                        vf[kk], pf[qt][kk], o_acc[qt][nt], 0, 0, 0);
        }
        __builtin_amdgcn_s_setprio(0);
        __syncthreads();  // drains prefetch DMAs; next tile ready
    }
    // lanes l31 and l31+32 hold complementary key subsets; combine denominators
#pragma unroll
    for (int qt = 0; qt < 2; ++qt) {
        float li = l_i[qt] + __shfl_xor(l_i[qt], 32, 64);
        float inv = 1.f / li;
        u16* orow =
            houtt + (size_t)(b * S + q0 + w * 64 + qt * 32 + l31) * 512 + h * HD;
#pragma unroll
        for (int nt = 0; nt < 2; ++nt)
#pragma unroll
            for (int g = 0; g < 4; ++g) {
                uint2 pk;
                pk.x = pack_bf2(o_acc[qt][nt][g * 4 + 0] * inv,
                                o_acc[qt][nt][g * 4 + 1] * inv);
                pk.y = pack_bf2(o_acc[qt][nt][g * 4 + 2] * inv,
                                o_acc[qt][nt][g * 4 + 3] * inv);
                // d = nt*32 + 8g + 4*half + [0..3]
                *reinterpret_cast<uint2*>(&orow[nt * 32 + g * 8 + half * 4]) = pk;
            }
    }
}

extern "C" void kernel_launch(void* const* d_in, const int* in_sizes, int n_in,
                              void* d_out, int out_size, void* d_ws, size_t ws_size,
                              hipStream_t stream) {
    const float* x      = (const float*)d_in[0];
    const float* gamma  = (const float*)d_in[1];
    const float* beta   = (const float*)d_in[2];
    const float* w_qkv  = (const float*)d_in[3];
    const float* b_qkv  = (const float*)d_in[4];
    const float* w_proj = (const float*)d_in[5];
    const float* b_proj = (const float*)d_in[6];
    float* out = (float*)d_out;

    char* ws = (char*)d_ws;
    u16* wbf   = (u16*)ws;                                  // 2 MB (qkv+proj bf16)
    u16* xnt   = (u16*)(ws + 2097152);                      // 8 MB [b][s][512]
    u16* qkvT  = (u16*)(ws + 2097152 + 8388608);            // 16 MB [b][s][1024]
    u16* qkvV  = (u16*)(ws + 2097152 + 8388608 + 16777216); // 8 MB [b][512][S]
    u16* houtt = xnt;  // alias: xnt dead after qkv GEMM

    prep<<<1280, 256, 0, stream>>>(x, w_qkv, w_proj, gamma, beta, wbf, xnt);
    qkv_gemm<<<dim3(8, 12, Bn), 256, 0, stream>>>(wbf, xnt, b_qkv, qkvT, qkvV);
    attn_mfma<<<dim3(Bn * NH, S / 128), 128, 0, stream>>>(qkvT, qkvV, houtt);
    proj_gemm<<<dim3(8, 8, Bn), 256, 0, stream>>>(
        wbf + 1536 * 512, houtt, b_proj, x, out);
}

// Round 4
// 149.605 us; speedup vs baseline: 1.0683x; 1.0683x over previous
//
#include <hip/hip_runtime.h>
#include <hip/hip_bf16.h>

typedef __hip_bfloat16 bf16;
typedef unsigned short u16;
typedef __attribute__((ext_vector_type(8))) short bf16x8;
typedef __attribute__((ext_vector_type(16))) float f32x16;

static constexpr int Bn = 8;
static constexpr int C = 512;
static constexpr int S = 1024;
static constexpr int NH = 8;
static constexpr int HD = 64;
static constexpr int CPG = 16;
#define EPSV 1e-5f
#define QSCALE 0.18033688011112042f  /* 0.125 * log2(e): folds attn scale + exp->exp2 */

__device__ __forceinline__ u16 f2bf(float f) {
    bf16 h = __float2bfloat16(f);
    return *reinterpret_cast<u16*>(&h);
}
__device__ __forceinline__ unsigned pack_bf2(float a, float b) {
    __hip_bfloat162 h = __float22bfloat162_rn(make_float2(a, b));
    return *reinterpret_cast<unsigned*>(&h);
}

// v_permlane32_swap_b32: x = {a.lo | b.lo-from-counterpart}, y = {a.hi-from-counterpart | b.hi}
__device__ __forceinline__ void plswap32(unsigned a, unsigned b, unsigned& x, unsigned& y) {
    typedef __attribute__((ext_vector_type(2))) int v2i;
    v2i r = __builtin_amdgcn_permlane32_swap((int)a, (int)b, false, false);
    x = (unsigned)r[0];
    y = (unsigned)r[1];
}

// async global->LDS, 16B per lane; LDS dest = wave-uniform base + lane*16
__device__ __forceinline__ void async_copy16(const void* g, void* l) {
    __builtin_amdgcn_global_load_lds(
        (const __attribute__((address_space(1))) void*)g,
        (__attribute__((address_space(3))) void*)l, 16, 0, 0);
}

// ---- prep: blocks 0-255 fused GroupNorm (stats + apply + transpose, group
//      staged in 64 KB LDS — x read ONCE); blocks 256-1279 weight fp32->bf16 ----
__global__ __launch_bounds__(256) void prep(const float* __restrict__ x,
                                            const float* __restrict__ wqkv,
                                            const float* __restrict__ wproj,
                                            const float* __restrict__ gamma,
                                            const float* __restrict__ beta,
                                            u16* __restrict__ wbf,
                                            u16* __restrict__ xnt) {
    const int tid = threadIdx.x;
    __shared__ float xs[CPG * S];  // 64 KB: [c][s] for this (b,g) group
    if (blockIdx.x < 256) {
        const int bg = blockIdx.x;         // b*32 + g
        const int b = bg >> 5, g = bg & 31;
        const size_t base = (size_t)bg * CPG * S;  // group contiguous in x[b][c][s]
        const int N = CPG * S;  // 16384
        float sum = 0.f, sq = 0.f;
        for (int i = tid * 4; i < N; i += 1024) {
            float4 v = *reinterpret_cast<const float4*>(&x[base + i]);
            sum += v.x + v.y + v.z + v.w;
            sq += v.x * v.x + v.y * v.y + v.z * v.z + v.w * v.w;
            *reinterpret_cast<float4*>(&xs[i]) = v;  // stride-1 b128: conflict-free
        }
#pragma unroll
        for (int off = 32; off > 0; off >>= 1) {
            sum += __shfl_down(sum, off, 64);
            sq  += __shfl_down(sq,  off, 64);
        }
        __shared__ float s0[4], s1[4];
        __shared__ float sgb[32];  // gamma*rstd-ready params: [0..15]=gamma,[16..31]=beta
        __shared__ float smu, srstd;
        if ((tid & 63) == 0) { s0[tid >> 6] = sum; s1[tid >> 6] = sq; }
        if (tid < 16) {
            sgb[tid] = gamma[g * CPG + tid];
            sgb[16 + tid] = beta[g * CPG + tid];
        }
        __syncthreads();
        if (tid == 0) {
            float a  = s0[0] + s0[1] + s0[2] + s0[3];
            float b2 = s1[0] + s1[1] + s1[2] + s1[3];
            float mu = a / (float)N;
            float var = fmaxf(b2 / (float)N - mu * mu, 0.f);
            smu = mu;
            srstd = rsqrtf(var + EPSV);
        }
        __syncthreads();
        const float mu = smu, rstd = srstd;
        // apply + transpose: xnt[b][s][g*16 + c], 16 B store per (s, half-group)
#pragma unroll
        for (int it = 0; it < 8; ++it) {
            int idx = it * 256 + tid;       // 2048 = 1024 s x 2 half-groups
            int s = idx >> 1, jh = idx & 1;
            u16 t8[8];
#pragma unroll
            for (int j = 0; j < 8; ++j) {
                int c = jh * 8 + j;
                float v = (xs[c * S + s] - mu) * rstd;  // bank=s%32, lane-pairs 2-way: free
                t8[j] = f2bf(v * sgb[c] + sgb[16 + c]);
            }
            *reinterpret_cast<uint4*>(&xnt[(size_t)(b * S + s) * C + g * CPG + jh * 8]) =
                *reinterpret_cast<uint4*>(t8);
        }
    } else {
        int idx = (blockIdx.x - 256) * 1024 + tid * 4;  // 2048*512 total
        float4 v;
        float sc = 1.f;
        if (idx < 1536 * 512) {
            v = *reinterpret_cast<const float4*>(&wqkv[idx]);
            if (idx < 512 * 512) sc = QSCALE;  // Q rows
        } else {
            v = *reinterpret_cast<const float4*>(&wproj[idx - 1536 * 512]);
        }
        u16 t[4] = {f2bf(v.x * sc), f2bf(v.y * sc), f2bf(v.z * sc), f2bf(v.w * sc)};
        *reinterpret_cast<uint2*>(&wbf[idx]) = *reinterpret_cast<uint2*>(t);
    }
}

// ---- qkv GEMM: 128x128 tile, BK=64, 2 barriers/iter, 32x32x16 MFMA ----
// o<1024 (q,k) -> qkvT[b][s][1024] transposed; o>=1024 (v) -> qkvV[b][512][S].
// 32x32 C/D: col=lane&31, row=(reg&3)+8*(reg>>2)+4*(lane>>5)  [m74/m101]
__global__ __launch_bounds__(256) void qkv_gemm(const u16* __restrict__ Wb,
                                                const u16* __restrict__ Xt,
                                                const float* __restrict__ bias,
                                                u16* __restrict__ qkvT,
                                                u16* __restrict__ qkvV) {
    const int K = 512;
    const int b = blockIdx.z, o0 = blockIdx.y * 128, s0 = blockIdx.x * 128;
    const int tid = threadIdx.x;
    const int lane = tid & 63, w = tid >> 6;
    const int l31 = lane & 31, half = lane >> 5;
    const int wr = w >> 1, wc = w & 1;
    __shared__ u16 As[128 * 64];  // [o][k-chunk]: chunk c at slot c^(row&7)
    __shared__ u16 Bs[128 * 64];
    f32x16 acc[2][2] = {};
    const u16* Xb = Xt + (size_t)(b * S + s0) * K;
    for (int k0 = 0; k0 < K; k0 += 64) {
#pragma unroll
        for (int i = 0; i < 4; ++i) {
            int ci = w * 4 + i;
            int r = ci * 8 + (lane >> 3);
            int c = (lane & 7) ^ (r & 7);
            async_copy16(&Wb[(size_t)(o0 + r) * K + k0 + c * 8], &As[ci * 512]);
            async_copy16(&Xb[(size_t)r * K + k0 + c * 8], &Bs[ci * 512]);
        }
        __syncthreads();
#pragma unroll
        for (int kk = 0; kk < 4; ++kk) {
            int c8 = kk * 2 + half;
            bf16x8 af[2], bfr[2];
#pragma unroll
            for (int mt = 0; mt < 2; ++mt) {
                int R = wr * 64 + mt * 32 + l31;
                af[mt] = *reinterpret_cast<const bf16x8*>(
                    &As[R * 64 + ((c8 ^ (R & 7)) << 3)]);
            }
#pragma unroll
            for (int nt = 0; nt < 2; ++nt) {
                int R = wc * 64 + nt * 32 + l31;
                bfr[nt] = *reinterpret_cast<const bf16x8*>(
                    &Bs[R * 64 + ((c8 ^ (R & 7)) << 3)]);
            }
#pragma unroll
            for (int mt = 0; mt < 2; ++mt)
#pragma unroll
                for (int nt = 0; nt < 2; ++nt)
                    acc[mt][nt] = __builtin_amdgcn_mfma_f32_32x32x16_bf16(
                        af[mt], bfr[nt], acc[mt][nt], 0, 0, 0);
        }
        __syncthreads();
    }
    if (o0 < 1024) {
        // q,k -> [b][s][1024]; q bias gets QSCALE (matches pre-scaled Q weights)
        float bsc = (o0 < 512) ? QSCALE : 1.f;
#pragma unroll
        for (int mt = 0; mt < 2; ++mt) {
#pragma unroll
            for (int g = 0; g < 4; ++g) {
                int o_b = o0 + wr * 64 + mt * 32 + g * 8 + half * 4;
                float4 bz = *reinterpret_cast<const float4*>(&bias[o_b]);
#pragma unroll
                for (int nt = 0; nt < 2; ++nt) {
                    int s = s0 + wc * 64 + nt * 32 + l31;
                    uint2 pk;
                    pk.x = pack_bf2(acc[mt][nt][g * 4 + 0] + bz.x * bsc,
                                    acc[mt][nt][g * 4 + 1] + bz.y * bsc);
                    pk.y = pack_bf2(acc[mt][nt][g * 4 + 2] + bz.z * bsc,
                                    acc[mt][nt][g * 4 + 3] + bz.w * bsc);
                    *reinterpret_cast<uint2*>(&qkvT[(size_t)(b * S + s) * 1024 + o_b]) = pk;
                }
            }
        }
    } else {
        // v -> [b][v-channel][S]
#pragma unroll
        for (int mt = 0; mt < 2; ++mt) {
#pragma unroll
            for (int g = 0; g < 4; ++g) {
                int o_b = o0 - 1024 + wr * 64 + mt * 32 + g * 8 + half * 4;
                float4 bz = *reinterpret_cast<const float4*>(&bias[1024 + o_b]);
                float bza[4] = {bz.x, bz.y, bz.z, bz.w};
#pragma unroll
                for (int nt = 0; nt < 2; ++nt) {
                    int s = s0 + wc * 64 + nt * 32 + l31;
#pragma unroll
                    for (int r = 0; r < 4; ++r)
                        qkvV[(size_t)(b * 512 + o_b + r) * S + s] =
                            f2bf(acc[mt][nt][g * 4 + r] + bza[r]);
                }
            }
        }
    }
}

// ---- proj GEMM: 64(o)x128(s) tile -> 512 blocks = 2/CU (latency hiding) ----
// fp32 output = acc + bias + residual (fp32 x).
__global__ __launch_bounds__(256) void proj_gemm(const u16* __restrict__ Wb,
                                                 const u16* __restrict__ Xt,
                                                 const float* __restrict__ bias,
                                                 const float* __restrict__ resid,
                                                 float* __restrict__ Yf) {
    const int K = 512;
    const int b = blockIdx.z, o0 = blockIdx.y * 64, s0 = blockIdx.x * 128;
    const int tid = threadIdx.x;
    const int lane = tid & 63, w = tid >> 6;
    const int l31 = lane & 31, half = lane >> 5;
    const int wr = w >> 1, wc = w & 1;   // wave: 32 o x 64 s
    __shared__ u16 As[64 * 64];   // 8 KB
    __shared__ u16 Bs[128 * 64];  // 16 KB
    f32x16 acc[2] = {};           // nt over s
    const u16* Xb = Xt + (size_t)(b * S + s0) * K;
    for (int k0 = 0; k0 < K; k0 += 64) {
#pragma unroll
        for (int i = 0; i < 2; ++i) {
            int ci = w * 2 + i;
            int r = ci * 8 + (lane >> 3);
            int c = (lane & 7) ^ (r & 7);
            async_copy16(&Wb[(size_t)(o0 + r) * K + k0 + c * 8], &As[ci * 512]);
        }
#pragma unroll
        for (int i = 0; i < 4; ++i) {
            int ci = w * 4 + i;
            int r = ci * 8 + (lane >> 3);
            int c = (lane & 7) ^ (r & 7);
            async_copy16(&Xb[(size_t)r * K + k0 + c * 8], &Bs[ci * 512]);
        }
        __syncthreads();
#pragma unroll
        for (int kk = 0; kk < 4; ++kk) {
            int c8 = kk * 2 + half;
            int Ra = wr * 32 + l31;
            bf16x8 af = *reinterpret_cast<const bf16x8*>(
                &As[Ra * 64 + ((c8 ^ (Ra & 7)) << 3)]);
#pragma unroll
            for (int nt = 0; nt < 2; ++nt) {
                int R = wc * 64 + nt * 32 + l31;
                bf16x8 bfr = *reinterpret_cast<const bf16x8*>(
                    &Bs[R * 64 + ((c8 ^ (R & 7)) << 3)]);
                acc[nt] = __builtin_amdgcn_mfma_f32_32x32x16_bf16(
                    af, bfr, acc[nt], 0, 0, 0);
            }
        }
        __syncthreads();
    }
#pragma unroll
    for (int g = 0; g < 4; ++g) {
        int o_b = o0 + wr * 32 + g * 8 + half * 4;
        float4 bz = *reinterpret_cast<const float4*>(&bias[o_b]);
        float bza[4] = {bz.x, bz.y, bz.z, bz.w};
#pragma unroll
        for (int nt = 0; nt < 2; ++nt) {
            int s = s0 + wc * 64 + nt * 32 + l31;
#pragma unroll
            for (int r = 0; r < 4; ++r) {
                size_t idx = (size_t)(b * C + o_b + r) * S + s;
                Yf[idx] = acc[nt][g * 4 + r] + bza[r] + resid[idx];
            }
        }
    }
}

// ---- MFMA flash attention: 128-query blocks, KVBLK=128, 32x32x16 ----
// Grid swizzle: blockIdx.x = b*8+h (stride-64 blocks share (b,h) -> same XCD).
// KVBLK=128: 8 sync points; 16-MFMA clusters under setprio; prefetch covered
// by ~2x compute. K/V stored as 2x 64-key sub-tiles so the verified
// chunk-swizzle (slot = c ^ (row&7)) is reused unchanged.
// T12: swapped QK^T -> P lane-local; cvt_pk + permlane32_swap builds PV
// B-fragments in-register (no P LDS round-trip).
__global__ __launch_bounds__(256, 2) void attn_mfma(const u16* __restrict__ qkvT,
                                                    const u16* __restrict__ qkvV,
                                                    u16* __restrict__ houtt) {
    const int b = blockIdx.x >> 3, h = blockIdx.x & 7, q0 = blockIdx.y * 128;
    const int tid = threadIdx.x;
    const int lane = tid & 63, w = tid >> 6;
    const int l31 = lane & 31, half = lane >> 5;
    __shared__ u16 ks[2][2][64 * 64];  // [buf][kh][key64][d64] chunk-swizzled
    __shared__ u16 vs[2][2][64 * 64];  // [buf][kh][d64][key64] chunk-swizzled

    const u16* qrow = qkvT + (size_t)(b * S + q0 + w * 32 + l31) * 1024 + h * HD;
    const u16* krow = qkvT + (size_t)b * S * 1024 + 512 + h * HD;
    const u16* vrow = qkvV + (size_t)(b * 512 + h * HD) * S;

    // Q fragments in registers: B[k][n], n=l31 (query), k = kk*16 + half*8 + j
    bf16x8 qfrag[4];
#pragma unroll
    for (int kk = 0; kk < 4; ++kk)
        qfrag[kk] = *reinterpret_cast<const bf16x8*>(&qrow[kk * 16 + half * 8]);

    const int r8 = lane >> 3;   // staging row within 8-row chunk-group
    const int cc = lane & 7;    // staging chunk col (pre-xor)

    // stage tile 0 (keys 0..127): 8 asyncs/lane
#pragma unroll
    for (int kh = 0; kh < 2; ++kh)
#pragma unroll
        for (int i = 0; i < 2; ++i) {
            int ci = w * 2 + i;
            int r = ci * 8 + r8;
            int c = cc ^ (r & 7);
            async_copy16(&krow[(size_t)(kh * 64 + r) * 1024 + c * 8], &ks[0][kh][ci * 512]);
            async_copy16(&vrow[(size_t)r * S + kh * 64 + c * 8], &vs[0][kh][ci * 512]);
        }
    __syncthreads();

    f32x16 o_acc[2] = {};
    float l_i = 0.f;

    for (int t = 0; t < 8; ++t) {
        const int cur = t & 1, nxt = cur ^ 1;
        if (t < 7) {
            int kt = (t + 1) * 128;
#pragma unroll
            for (int kh = 0; kh < 2; ++kh)
#pragma unroll
                for (int i = 0; i < 2; ++i) {
                    int ci = w * 2 + i;
                    int r = ci * 8 + r8;
                    int c = cc ^ (r & 7);
                    async_copy16(&krow[(size_t)(kt + kh * 64 + r) * 1024 + c * 8],
                                 &ks[nxt][kh][ci * 512]);
                    async_copy16(&vrow[(size_t)r * S + kt + kh * 64 + c * 8],
                                 &vs[nxt][kh][ci * 512]);
                }
        }
        // ---- S^T = K Q^T over 128 keys: a-th 32-key slice, rows = keys ----
        f32x16 s_acc[4] = {};
        __builtin_amdgcn_s_setprio(1);
#pragma unroll
        for (int a = 0; a < 4; ++a) {
            int r = (a & 1) * 32 + l31;  // row within 64-key sub-tile
            const u16* kbase = &ks[cur][a >> 1][0];
#pragma unroll
            for (int kk = 0; kk < 4; ++kk) {
                int c8 = kk * 2 + half;
                bf16x8 kf = *reinterpret_cast<const bf16x8*>(
                    &kbase[r * 64 + ((c8 ^ (r & 7)) << 3)]);
                s_acc[a] = __builtin_amdgcn_mfma_f32_32x32x16_bf16(
                    kf, qfrag[kk], s_acc[a], 0, 0, 0);
            }
        }
        __builtin_amdgcn_s_setprio(0);
        // ---- max-free softmax: p = 2^s, in registers ----
        // lane (l31,half) holds P[q=l31][key = a*32 + g*8 + half*4 + r]
        float rsp0 = 0.f, rsp1 = 0.f, rsp2 = 0.f, rsp3 = 0.f;
#pragma unroll
        for (int a = 0; a < 4; ++a)
#pragma unroll
            for (int g = 0; g < 4; ++g) {
                float p0 = __builtin_amdgcn_exp2f(s_acc[a][g * 4 + 0]);
                float p1 = __builtin_amdgcn_exp2f(s_acc[a][g * 4 + 1]);
                float p2 = __builtin_amdgcn_exp2f(s_acc[a][g * 4 + 2]);
                float p3 = __builtin_amdgcn_exp2f(s_acc[a][g * 4 + 3]);
                s_acc[a][g * 4 + 0] = p0;
                s_acc[a][g * 4 + 1] = p1;
                s_acc[a][g * 4 + 2] = p2;
                s_acc[a][g * 4 + 3] = p3;
                rsp0 += p0; rsp1 += p1; rsp2 += p2; rsp3 += p3;
            }
        l_i += (rsp0 + rsp1) + (rsp2 + rsp3);
        // ---- P^T B-frags in-register: pf[kk][j] = P[q=l31][kk*16 + half*8 + j]
        // j0-3 from half-0-owned values, j4-7 from half-1-owned via permlane swap.
        bf16x8 pf[8];
#pragma unroll
        for (int a = 0; a < 4; ++a)
#pragma unroll
            for (int gp = 0; gp < 2; ++gp) {
                unsigned a_lo = pack_bf2(s_acc[a][gp * 8 + 0], s_acc[a][gp * 8 + 1]);
                unsigned a_hi = pack_bf2(s_acc[a][gp * 8 + 2], s_acc[a][gp * 8 + 3]);
                unsigned b_lo = pack_bf2(s_acc[a][gp * 8 + 4], s_acc[a][gp * 8 + 5]);
                unsigned b_hi = pack_bf2(s_acc[a][gp * 8 + 6], s_acc[a][gp * 8 + 7]);
                unsigned u0, u1, u2, u3;
                plswap32(a_lo, b_lo, u0, u2);
                plswap32(a_hi, b_hi, u1, u3);
                union { unsigned u[4]; bf16x8 v; } wv;
                wv.u[0] = u0; wv.u[1] = u1; wv.u[2] = u2; wv.u[3] = u3;
                pf[a * 2 + gp] = wv.v;
            }
        // ---- O^T += V^T P^T over 128 keys: rows = d, cols = 32 queries ----
        __builtin_amdgcn_s_setprio(1);
#pragma unroll
        for (int nt = 0; nt < 2; ++nt) {
            int rv = nt * 32 + l31;
#pragma unroll
            for (int kk = 0; kk < 8; ++kk) {
                int c8 = kk * 2 + half;           // key-chunk 0..15
                const u16* vbase = &vs[cur][c8 >> 3][0];
                int c8l = c8 & 7;
                bf16x8 vf = *reinterpret_cast<const bf16x8*>(
                    &vbase[rv * 64 + ((c8l ^ (rv & 7)) << 3)]);
                o_acc[nt] = __builtin_amdgcn_mfma_f32_32x32x16_bf16(
                    vf, pf[kk], o_acc[nt], 0, 0, 0);
            }
        }
        __builtin_amdgcn_s_setprio(0);
        __syncthreads();  // drains prefetch DMAs; next tile ready
    }
    // lanes l31 and l31+32 hold complementary key subsets; combine denominators
    l_i += __shfl_xor(l_i, 32, 64);
    float inv = 1.f / l_i;
    u16* orow = houtt + (size_t)(b * S + q0 + w * 32 + l31) * 512 + h * HD;
#pragma unroll
    for (int nt = 0; nt < 2; ++nt)
#pragma unroll
        for (int g = 0; g < 4; ++g) {
            uint2 pk;
            pk.x = pack_bf2(o_acc[nt][g * 4 + 0] * inv, o_acc[nt][g * 4 + 1] * inv);
            pk.y = pack_bf2(o_acc[nt][g * 4 + 2] * inv, o_acc[nt][g * 4 + 3] * inv);
            // d = nt*32 + 8g + 4*half + [0..3]
            *reinterpret_cast<uint2*>(&orow[nt * 32 + g * 8 + half * 4]) = pk;
        }
}

extern "C" void kernel_launch(void* const* d_in, const int* in_sizes, int n_in,
                              void* d_out, int out_size, void* d_ws, size_t ws_size,
                              hipStream_t stream) {
    const float* x      = (const float*)d_in[0];
    const float* gamma  = (const float*)d_in[1];
    const float* beta   = (const float*)d_in[2];
    const float* w_qkv  = (const float*)d_in[3];
    const float* b_qkv  = (const float*)d_in[4];
    const float* w_proj = (const float*)d_in[5];
    const float* b_proj = (const float*)d_in[6];
    float* out = (float*)d_out;

    char* ws = (char*)d_ws;
    u16* wbf   = (u16*)ws;                                  // 2 MB (qkv+proj bf16)
    u16* xnt   = (u16*)(ws + 2097152);                      // 8 MB [b][s][512]
    u16* qkvT  = (u16*)(ws + 2097152 + 8388608);            // 16 MB [b][s][1024]
    u16* qkvV  = (u16*)(ws + 2097152 + 8388608 + 16777216); // 8 MB [b][512][S]
    u16* houtt = xnt;  // alias: xnt dead after qkv GEMM

    prep<<<1280, 256, 0, stream>>>(x, w_qkv, w_proj, gamma, beta, wbf, xnt);
    qkv_gemm<<<dim3(8, 12, Bn), 256, 0, stream>>>(wbf, xnt, b_qkv, qkvT, qkvV);
    attn_mfma<<<dim3(Bn * NH, S / 128), 256, 0, stream>>>(qkvT, qkvV, houtt);
    proj_gemm<<<dim3(8, 8, Bn), 256, 0, stream>>>(
        wbf + 1536 * 512, houtt, b_proj, x, out);
}